// Round 11
// baseline (534.168 us; speedup 1.0000x reference)
//
#include <hip/hip_runtime.h>
#include <hip/hip_bf16.h>

#define D_FEAT 768
#define SLOT 128      // fixed CSR slots per node
#define NBLK 512      // persistent grid: 2 blocks/CU x 256 CUs, co-resident by launch_bounds

typedef __bf16 bf16x8 __attribute__((ext_vector_type(8)));
typedef float floatx4 __attribute__((ext_vector_type(4)));

__device__ __forceinline__ float bf2f(unsigned short u) {
    unsigned int x = ((unsigned int)u) << 16;
    return __builtin_bit_cast(float, x);
}
__device__ __forceinline__ unsigned short f2bf(float f) {
    unsigned int x = __builtin_bit_cast(unsigned int, f);
    unsigned int lsb = (x >> 16) & 1u;
    x += 0x7fffu + lsb;            // round-to-nearest-even
    return (unsigned short)(x >> 16);
}
__device__ __forceinline__ void async_ld16(const void* g, void* l) {
    __builtin_amdgcn_global_load_lds(
        (__attribute__((address_space(1))) void*)(g),
        (__attribute__((address_space(3))) void*)(l), 16, 0, 0);
}

struct Params {
    const float* x; const int* src; const int* dst;
    const float *W1, *as1, *ad1, *b1, *W2, *as2, *ad2, *b2;
    unsigned short *Wt1, *Wt2, *xb, *h, *x2b;
    float *us1, *ud1, *us2, *ud2, *es1, *ed1, *es2, *ed2;
    int *cur, *col;
    int *gbar, *ctr;    // gbar[4] barriers, ctr[2] work-steal counters (zeroed by init)
    float* out;
    int N, E, n8, mT;   // mT = (N+127)/128
};

// ---- manual grid barrier (agent scope: cross-XCD wb/inv on release/acquire) --
__device__ __forceinline__ void gbarrier(int* ctr) {
    __syncthreads();                 // drains this block's memory ops (vmcnt/lgkm)
    if (threadIdx.x == 0) {
        __hip_atomic_fetch_add(ctr, 1, __ATOMIC_ACQ_REL, __HIP_MEMORY_SCOPE_AGENT);
        while (__hip_atomic_load(ctr, __ATOMIC_ACQUIRE, __HIP_MEMORY_SCOPE_AGENT) < NBLK)
            __builtin_amdgcn_s_sleep(8);
    }
    __syncthreads();
}

// ---- single-buffer 128x128 GEMM tile (round-8 verified) ---------------------
__device__ __forceinline__ void gemm_tile(
    const unsigned short* __restrict__ A, const unsigned short* __restrict__ Bt,
    unsigned short* __restrict__ C, int M, int m0, int n0,
    unsigned short* sA, unsigned short* sB)
{
    const int tid = threadIdx.x;
    const int lane = tid & 63, wave = tid >> 6;
    const int wm = wave >> 1, wn = wave & 1;
    const int l15 = lane & 15, quad = lane >> 4;

    const int srow = lane >> 2;
    const int scol = (lane & 3) * 8;
    int ar0 = m0 + wave * 32 + srow;      if (ar0 >= M) ar0 = M - 1;
    int ar1 = m0 + wave * 32 + 16 + srow; if (ar1 >= M) ar1 = M - 1;
    const unsigned short* aptr0 = A + (size_t)ar0 * 768 + scol;
    const unsigned short* aptr1 = A + (size_t)ar1 * 768 + scol;
    const unsigned short* bptr0 = Bt + (size_t)(n0 + wave * 32 + srow) * 768 + scol;
    const unsigned short* bptr1 = bptr0 + (size_t)16 * 768;
    char* aldst = (char*)sA + wave * 2048;
    char* bldst = (char*)sB + wave * 2048;

    floatx4 acc[4][4];
    #pragma unroll
    for (int i = 0; i < 4; ++i)
        #pragma unroll
        for (int j = 0; j < 4; ++j)
            acc[i][j] = (floatx4){0.f, 0.f, 0.f, 0.f};

    for (int kt = 0; kt < 768; kt += 32) {
        __syncthreads();
        async_ld16(aptr0 + kt, aldst);
        async_ld16(aptr1 + kt, aldst + 1024);
        async_ld16(bptr0 + kt, bldst);
        async_ld16(bptr1 + kt, bldst + 1024);
        __syncthreads();

        bf16x8 af[4], bfr[4];
        #pragma unroll
        for (int i = 0; i < 4; ++i)
            af[i] = *(const bf16x8*)&sA[(wm * 64 + i * 16 + l15) * 32 + quad * 8];
        #pragma unroll
        for (int j = 0; j < 4; ++j)
            bfr[j] = *(const bf16x8*)&sB[(wn * 64 + j * 16 + l15) * 32 + quad * 8];
        #pragma unroll
        for (int i = 0; i < 4; ++i)
            #pragma unroll
            for (int j = 0; j < 4; ++j)
                acc[i][j] = __builtin_amdgcn_mfma_f32_16x16x32_bf16(af[i], bfr[j], acc[i][j], 0, 0, 0);
    }
    __syncthreads();   // protect LDS before any next use

    #pragma unroll
    for (int i = 0; i < 4; ++i)
        #pragma unroll
        for (int r = 0; r < 4; ++r) {
            int m = m0 + wm * 64 + i * 16 + quad * 4 + r;   // row = quad*4+reg
            if (m < M) {
                #pragma unroll
                for (int j = 0; j < 4; ++j)
                    C[(size_t)m * 768 + n0 + wn * 64 + j * 16 + l15] = f2bf(acc[i][j][r]);
            }
        }
}

// ---- wave-per-node agg unit (4 nodes/unit; no block barriers inside) --------
__device__ __forceinline__ void agg_unit(
    int unit, const Params& p,
    const unsigned short* __restrict__ h, const float* __restrict__ es,
    const float* __restrict__ ed, const float* __restrict__ bias,
    unsigned short* __restrict__ out_bf, float* __restrict__ out_f,
    const float* __restrict__ us2, const float* __restrict__ ud2,
    float* __restrict__ es2, float* __restrict__ ed2)
{
    int wid = threadIdx.x >> 6, lane = threadIdx.x & 63;
    int n = unit * 4 + wid;
    if (n >= p.N) return;
    int deg = p.cur[n]; if (deg > SLOT) deg = SLOT;
    int beg = n * SLOT;
    float edn = ed[n];

    float a[12];
    #pragma unroll
    for (int k = 0; k < 12; ++k) a[k] = 0.f;
    const unsigned short* hb = h + lane * 12;

    if (deg <= 64) {
        int s = 0; float v = -3.4e38f;
        if (lane < deg) {
            s = p.col[beg + lane];
            v = es[s] + edn;
            v = v > 0.f ? v : 0.2f * v;
        }
        float lm = v;
        #pragma unroll
        for (int m = 32; m >= 1; m >>= 1) lm = fmaxf(lm, __shfl_xor(lm, m, 64));
        float w = (lane < deg) ? __expf(v - lm) : 0.f;
        float ls = w;
        #pragma unroll
        for (int m = 32; m >= 1; m >>= 1) ls += __shfl_xor(ls, m, 64);
        w *= (1.f / ls);

        int i = 0;
        for (; i + 4 <= deg; i += 4) {
            #pragma unroll
            for (int u = 0; u < 4; ++u) {
                int   su = __shfl(s, i + u, 64);
                float wu = __shfl(w, i + u, 64);
                const unsigned short* hr = hb + (size_t)su * 768;
                ushort4 p0 = *(const ushort4*)(hr);
                ushort4 p1 = *(const ushort4*)(hr + 4);
                ushort4 p2 = *(const ushort4*)(hr + 8);
                a[0]  += wu * bf2f(p0.x); a[1]  += wu * bf2f(p0.y);
                a[2]  += wu * bf2f(p0.z); a[3]  += wu * bf2f(p0.w);
                a[4]  += wu * bf2f(p1.x); a[5]  += wu * bf2f(p1.y);
                a[6]  += wu * bf2f(p1.z); a[7]  += wu * bf2f(p1.w);
                a[8]  += wu * bf2f(p2.x); a[9]  += wu * bf2f(p2.y);
                a[10] += wu * bf2f(p2.z); a[11] += wu * bf2f(p2.w);
            }
        }
        for (; i < deg; ++i) {
            int   s0 = __shfl(s, i, 64);
            float w0 = __shfl(w, i, 64);
            const unsigned short* h0 = hb + (size_t)s0 * 768;
            ushort4 p0 = *(const ushort4*)(h0);
            ushort4 p1 = *(const ushort4*)(h0 + 4);
            ushort4 p2 = *(const ushort4*)(h0 + 8);
            a[0]  += w0 * bf2f(p0.x); a[1]  += w0 * bf2f(p0.y);
            a[2]  += w0 * bf2f(p0.z); a[3]  += w0 * bf2f(p0.w);
            a[4]  += w0 * bf2f(p1.x); a[5]  += w0 * bf2f(p1.y);
            a[6]  += w0 * bf2f(p1.z); a[7]  += w0 * bf2f(p1.w);
            a[8]  += w0 * bf2f(p2.x); a[9]  += w0 * bf2f(p2.y);
            a[10] += w0 * bf2f(p2.z); a[11] += w0 * bf2f(p2.w);
        }
    } else {
        float lm = -3.4e38f;
        for (int i = lane; i < deg; i += 64) {
            float v = es[p.col[beg + i]] + edn;
            v = v > 0.f ? v : 0.2f * v;
            lm = fmaxf(lm, v);
        }
        #pragma unroll
        for (int m = 32; m >= 1; m >>= 1) lm = fmaxf(lm, __shfl_xor(lm, m, 64));
        float ls = 0.f;
        for (int i = lane; i < deg; i += 64) {
            float v = es[p.col[beg + i]] + edn;
            v = v > 0.f ? v : 0.2f * v;
            ls += __expf(v - lm);
        }
        #pragma unroll
        for (int m = 32; m >= 1; m >>= 1) ls += __shfl_xor(ls, m, 64);
        float rz = 1.f / ls;
        for (int i = 0; i < deg; ++i) {
            int sidx = p.col[beg + i];
            float u = es[sidx] + edn;
            u = u > 0.f ? u : 0.2f * u;
            float w = __expf(u - lm) * rz;
            const unsigned short* hr = hb + (size_t)sidx * 768;
            ushort4 v0 = *(const ushort4*)(hr);
            ushort4 v1 = *(const ushort4*)(hr + 4);
            ushort4 v2 = *(const ushort4*)(hr + 8);
            a[0]  += w * bf2f(v0.x); a[1]  += w * bf2f(v0.y);
            a[2]  += w * bf2f(v0.z); a[3]  += w * bf2f(v0.w);
            a[4]  += w * bf2f(v1.x); a[5]  += w * bf2f(v1.y);
            a[6]  += w * bf2f(v1.z); a[7]  += w * bf2f(v1.w);
            a[8]  += w * bf2f(v2.x); a[9]  += w * bf2f(v2.y);
            a[10] += w * bf2f(v2.z); a[11] += w * bf2f(v2.w);
        }
    }

    float4 bv0 = *(const float4*)&bias[lane * 12];
    float4 bv1 = *(const float4*)&bias[lane * 12 + 4];
    float4 bv2 = *(const float4*)&bias[lane * 12 + 8];
    float o[12];
    o[0] = a[0] + bv0.x; o[1] = a[1] + bv0.y; o[2] = a[2] + bv0.z; o[3] = a[3] + bv0.w;
    o[4] = a[4] + bv1.x; o[5] = a[5] + bv1.y; o[6] = a[6] + bv1.z; o[7] = a[7] + bv1.w;
    o[8] = a[8] + bv2.x; o[9] = a[9] + bv2.y; o[10] = a[10] + bv2.z; o[11] = a[11] + bv2.w;
    size_t base = (size_t)n * 768 + lane * 12;
    if (out_bf) {   // layer 1: relu + bf16; fused es2/ed2 dots
        #pragma unroll
        for (int k = 0; k < 12; ++k) o[k] = fmaxf(o[k], 0.f);
        float ps = 0.f, pd = 0.f;
        #pragma unroll
        for (int c = 0; c < 3; ++c) {
            int off = lane * 12 + c * 4;
            float4 u = *(const float4*)(us2 + off);
            float4 w = *(const float4*)(ud2 + off);
            ps += o[c*4] * u.x + o[c*4+1] * u.y + o[c*4+2] * u.z + o[c*4+3] * u.w;
            pd += o[c*4] * w.x + o[c*4+1] * w.y + o[c*4+2] * w.z + o[c*4+3] * w.w;
        }
        #pragma unroll
        for (int m = 32; m >= 1; m >>= 1) {
            ps += __shfl_xor(ps, m, 64); pd += __shfl_xor(pd, m, 64);
        }
        if (lane == 0) { es2[n] = ps; ed2[n] = pd; }
        ushort4 w0, w1, w2;
        w0.x = f2bf(o[0]); w0.y = f2bf(o[1]); w0.z = f2bf(o[2]); w0.w = f2bf(o[3]);
        w1.x = f2bf(o[4]); w1.y = f2bf(o[5]); w1.z = f2bf(o[6]); w1.w = f2bf(o[7]);
        w2.x = f2bf(o[8]); w2.y = f2bf(o[9]); w2.z = f2bf(o[10]); w2.w = f2bf(o[11]);
        *(ushort4*)&out_bf[base] = w0;
        *(ushort4*)&out_bf[base + 4] = w1;
        *(ushort4*)&out_bf[base + 8] = w2;
    } else {        // layer 2: f32 final output
        float4 f0 = {o[0], o[1], o[2], o[3]};
        float4 f1 = {o[4], o[5], o[6], o[7]};
        float4 f2 = {o[8], o[9], o[10], o[11]};
        *(float4*)&out_f[base] = f0;
        *(float4*)&out_f[base + 4] = f1;
        *(float4*)&out_f[base + 8] = f2;
    }
}

// ---- zero the sync words (ws is 0xAA-poisoned before every call) ------------
__global__ void init_kernel(int* g) {
    if (threadIdx.x < 8) g[threadIdx.x] = 0;
}

// ---- the persistent mega-kernel (plain launch + manual barriers) ------------
__global__ __launch_bounds__(256, 2) void mega_kernel(Params p)
{
    __shared__ __align__(16) unsigned short smem[8192];   // 16 KB
    __shared__ int s_u;
    unsigned short* sA = smem;
    unsigned short* sB = smem + 4096;
    const int tid = threadIdx.x;
    const int lane = tid & 63;

    // ===== PHASE 0 (work-steal): W transpose | matvec | x conv + cur=0 ======
    {
        const int T = 1152, V = 192;
        const int cB = (p.n8 + 255) / 256;
        const int U0 = T + V + cB;
        for (;;) {
            __syncthreads();
            if (tid == 0) s_u = atomicAdd(&p.ctr[0], 1);
            __syncthreads();
            int u = s_u;
            if (u >= U0) break;
            if (u < T) {
                const float* W = (u >= 576) ? p.W2 : p.W1;
                unsigned short* Wt = (u >= 576) ? p.Wt2 : p.Wt1;
                int rem = (u >= 576) ? u - 576 : u;
                float* tile = (float*)smem;               // 32x33 f32
                int x0 = (rem % 24) * 32, y0 = (rem / 24) * 32;
                int tx = tid & 31, ty = tid >> 5;
                for (int r = ty; r < 32; r += 8)
                    tile[r * 33 + tx] = W[(size_t)(y0 + r) * D_FEAT + x0 + tx];
                __syncthreads();
                for (int r = ty; r < 32; r += 8)
                    Wt[(size_t)(x0 + r) * D_FEAT + y0 + tx] = f2bf(tile[tx * 33 + r]);
            } else if (u < T + V) {
                int k = (u - T) * 4 + (tid >> 6);
                const float* r1 = p.W1 + (size_t)k * D_FEAT + lane * 12;
                const float* r2 = p.W2 + (size_t)k * D_FEAT + lane * 12;
                float s1 = 0.f, d1 = 0.f, s2 = 0.f, d2 = 0.f;
                #pragma unroll
                for (int c = 0; c < 3; ++c) {
                    float4 w1v = *(const float4*)(r1 + c * 4);
                    float4 w2v = *(const float4*)(r2 + c * 4);
                    int off = lane * 12 + c * 4;
                    float4 a1 = *(const float4*)(p.as1 + off);
                    float4 b1v = *(const float4*)(p.ad1 + off);
                    float4 a2 = *(const float4*)(p.as2 + off);
                    float4 b2v = *(const float4*)(p.ad2 + off);
                    s1 += w1v.x * a1.x + w1v.y * a1.y + w1v.z * a1.z + w1v.w * a1.w;
                    d1 += w1v.x * b1v.x + w1v.y * b1v.y + w1v.z * b1v.z + w1v.w * b1v.w;
                    s2 += w2v.x * a2.x + w2v.y * a2.y + w2v.z * a2.z + w2v.w * a2.w;
                    d2 += w2v.x * b2v.x + w2v.y * b2v.y + w2v.z * b2v.z + w2v.w * b2v.w;
                }
                #pragma unroll
                for (int m = 32; m >= 1; m >>= 1) {
                    s1 += __shfl_xor(s1, m, 64); d1 += __shfl_xor(d1, m, 64);
                    s2 += __shfl_xor(s2, m, 64); d2 += __shfl_xor(d2, m, 64);
                }
                if (lane == 0) { p.us1[k] = s1; p.ud1[k] = d1; p.us2[k] = s2; p.ud2[k] = d2; }
            } else {
                int li = (u - T - V) * 256 + tid;
                if (li < p.n8) {
                    float4 v0 = ((const float4*)p.x)[li * 2];
                    float4 v1 = ((const float4*)p.x)[li * 2 + 1];
                    ushort4 o0, o1;
                    o0.x = f2bf(v0.x); o0.y = f2bf(v0.y); o0.z = f2bf(v0.z); o0.w = f2bf(v0.w);
                    o1.x = f2bf(v1.x); o1.y = f2bf(v1.y); o1.z = f2bf(v1.z); o1.w = f2bf(v1.w);
                    ((ushort4*)p.xb)[li * 2] = o0;
                    ((ushort4*)p.xb)[li * 2 + 1] = o1;
                }
                if (li < p.N) p.cur[li] = 0;
            }
        }
    }
    gbarrier(&p.gbar[0]);

    // ===== PHASE 1 (work-steal): GEMM-1 | CSR fill | layer-1 dots ===========
    {
        const int GB = p.mT * 6;
        const int fB = (p.E + p.N + 255) / 256;
        const int dB = (p.N + 3) / 4;
        const int U1 = GB + fB + dB;
        for (;;) {
            __syncthreads();
            if (tid == 0) s_u = atomicAdd(&p.ctr[1], 1);
            __syncthreads();
            int u = s_u;
            if (u >= U1) break;
            if (u < GB) {
                gemm_tile(p.xb, p.Wt1, p.h, p.N, (u / 6) * 128, (u % 6) * 128, sA, sB);
            } else if (u < GB + fB) {
                int i = (u - GB) * 256 + tid;
                if (i < p.E + p.N) {
                    int s, d;
                    if (i < p.E) { s = p.src[i]; d = p.dst[i]; } else { s = i - p.E; d = s; }
                    int pos = atomicAdd(&p.cur[d], 1);
                    if (pos < SLOT) p.col[d * SLOT + pos] = s;
                }
            } else {
                int n = (u - GB - fB) * 4 + (tid >> 6);
                if (n < p.N) {
                    const unsigned short* xr = p.xb + (size_t)n * D_FEAT + lane * 12;
                    float s = 0.f, d = 0.f;
                    #pragma unroll
                    for (int c = 0; c < 3; ++c) {
                        ushort4 v = *(const ushort4*)(xr + c * 4);
                        int off = lane * 12 + c * 4;
                        float4 uu = *(const float4*)(p.us1 + off);
                        float4 w = *(const float4*)(p.ud1 + off);
                        float f0 = bf2f(v.x), f1 = bf2f(v.y), f2v = bf2f(v.z), f3 = bf2f(v.w);
                        s += f0 * uu.x + f1 * uu.y + f2v * uu.z + f3 * uu.w;
                        d += f0 * w.x + f1 * w.y + f2v * w.z + f3 * w.w;
                    }
                    #pragma unroll
                    for (int m = 32; m >= 1; m >>= 1) {
                        s += __shfl_xor(s, m, 64); d += __shfl_xor(d, m, 64);
                    }
                    if (lane == 0) { p.es1[n] = s; p.ed1[n] = d; }
                }
            }
        }
    }
    gbarrier(&p.gbar[1]);

    // ===== PHASE 2: agg layer 1 (+fused es2/ed2) ============================
    {
        const int dB = (p.N + 3) / 4;
        for (int u = blockIdx.x; u < dB; u += NBLK)
            agg_unit(u, p, p.h, p.es1, p.ed1, p.b1, p.x2b, nullptr,
                     p.us2, p.ud2, p.es2, p.ed2);
    }
    gbarrier(&p.gbar[2]);

    // ===== PHASE 3: GEMM-2 ==================================================
    {
        const int GB = p.mT * 6;
        for (int u = blockIdx.x; u < GB; u += NBLK)
            gemm_tile(p.x2b, p.Wt2, p.h, p.N, (u / 6) * 128, (u % 6) * 128, sA, sB);
    }
    gbarrier(&p.gbar[3]);

    // ===== PHASE 4: agg layer 2 -> f32 out ==================================
    {
        const int dB = (p.N + 3) / 4;
        for (int u = blockIdx.x; u < dB; u += NBLK)
            agg_unit(u, p, p.h, p.es2, p.ed2, p.b2, nullptr, p.out,
                     nullptr, nullptr, nullptr, nullptr);
    }
}

// -----------------------------------------------------------------------------
extern "C" void kernel_launch(void* const* d_in, const int* in_sizes, int n_in,
                              void* d_out, int out_size, void* d_ws, size_t ws_size,
                              hipStream_t stream)
{
    Params p;
    p.x   = (const float*)d_in[0];
    const int* ei = (const int*)d_in[1];
    p.W1  = (const float*)d_in[2];
    p.as1 = (const float*)d_in[3];
    p.ad1 = (const float*)d_in[4];
    p.b1  = (const float*)d_in[5];
    p.W2  = (const float*)d_in[6];
    p.as2 = (const float*)d_in[7];
    p.ad2 = (const float*)d_in[8];
    p.b2  = (const float*)d_in[9];

    p.N = in_sizes[0] / D_FEAT;
    p.E = in_sizes[1] / 2;
    p.src = ei;
    p.dst = ei + p.E;
    p.n8 = p.N * D_FEAT / 8;
    p.mT = (p.N + 127) / 128;
    p.out = (float*)d_out;

    char* ws = (char*)d_ws;
    size_t off = 0;
    auto alloc = [&](size_t bytes) -> void* {
        void* q = ws + off;
        off += (bytes + 255) & ~(size_t)255;
        return q;
    };
    p.Wt1 = (unsigned short*)alloc((size_t)768 * 768 * 2);
    p.Wt2 = (unsigned short*)alloc((size_t)768 * 768 * 2);
    p.xb  = (unsigned short*)alloc((size_t)p.N * 768 * 2);
    p.h   = (unsigned short*)alloc((size_t)p.N * 768 * 2);
    p.x2b = (unsigned short*)alloc((size_t)p.N * 768 * 2);
    p.us1 = (float*)alloc((size_t)768 * 4);
    p.ud1 = (float*)alloc((size_t)768 * 4);
    p.us2 = (float*)alloc((size_t)768 * 4);
    p.ud2 = (float*)alloc((size_t)768 * 4);
    p.es1 = (float*)alloc((size_t)p.N * 4);
    p.ed1 = (float*)alloc((size_t)p.N * 4);
    p.es2 = (float*)alloc((size_t)p.N * 4);
    p.ed2 = (float*)alloc((size_t)p.N * 4);
    p.cur = (int*)alloc((size_t)p.N * 4);
    p.col = (int*)alloc((size_t)p.N * SLOT * 4);
    int* gsync = (int*)alloc(64);
    p.gbar = gsync;       // [0..3]
    p.ctr  = gsync + 4;   // [4..5]

    init_kernel<<<1, 64, 0, stream>>>(gsync);
    mega_kernel<<<NBLK, 256, 0, stream>>>(p);
}

// Round 12
// 201.309 us; speedup vs baseline: 2.6535x; 2.6535x over previous
//
#include <hip/hip_runtime.h>
#include <hip/hip_bf16.h>

#define D_FEAT 768
#define SLOT 128   // fixed CSR slots per node

typedef __bf16 bf16x8 __attribute__((ext_vector_type(8)));
typedef float floatx4 __attribute__((ext_vector_type(4)));

__device__ __forceinline__ float bf2f(unsigned short u) {
    unsigned int x = ((unsigned int)u) << 16;
    return __builtin_bit_cast(float, x);
}
__device__ __forceinline__ unsigned short f2bf(float f) {
    unsigned int x = __builtin_bit_cast(unsigned int, f);
    unsigned int lsb = (x >> 16) & 1u;
    x += 0x7fffu + lsb;            // round-to-nearest-even
    return (unsigned short)(x >> 16);
}
__device__ __forceinline__ void async_ld16(const void* g, void* l) {
    __builtin_amdgcn_global_load_lds(
        (__attribute__((address_space(1))) void*)(g),
        (__attribute__((address_space(3))) void*)(l), 16, 0, 0);
}

// ---- 128x128 GEMM tile, 2 x BK=32 panels per barrier pair -------------------
// sA/sB hold two 128x32 panels (8 KB each panel). 12 barrier pairs for K=768;
// 8 loads/wave in flight per stage, 32 MFMA per drain (2x R8's amortization).
__device__ __forceinline__ void gemm_tile(
    const unsigned short* __restrict__ A, const unsigned short* __restrict__ Bt,
    unsigned short* __restrict__ C, int M, int m0, int n0,
    unsigned short* sA, unsigned short* sB)
{
    const int tid = threadIdx.x;
    const int lane = tid & 63, wave = tid >> 6;
    const int wm = wave >> 1, wn = wave & 1;
    const int l15 = lane & 15, quad = lane >> 4;

    const int srow = lane >> 2;              // 0..15
    const int scol = (lane & 3) * 8;         // element col
    int ar0 = m0 + wave * 32 + srow;      if (ar0 >= M) ar0 = M - 1;
    int ar1 = m0 + wave * 32 + 16 + srow; if (ar1 >= M) ar1 = M - 1;
    const unsigned short* aptr0 = A + (size_t)ar0 * 768 + scol;
    const unsigned short* aptr1 = A + (size_t)ar1 * 768 + scol;
    const unsigned short* bptr0 = Bt + (size_t)(n0 + wave * 32 + srow) * 768 + scol;
    const unsigned short* bptr1 = bptr0 + (size_t)16 * 768;

    floatx4 acc[4][4];
    #pragma unroll
    for (int i = 0; i < 4; ++i)
        #pragma unroll
        for (int j = 0; j < 4; ++j)
            acc[i][j] = (floatx4){0.f, 0.f, 0.f, 0.f};

    for (int kt = 0; kt < 768; kt += 64) {
        __syncthreads();
        #pragma unroll
        for (int ks = 0; ks < 2; ++ks) {
            const int ko = kt + ks * 32;
            char* a_d = (char*)sA + ks * 8192 + wave * 2048;
            char* b_d = (char*)sB + ks * 8192 + wave * 2048;
            async_ld16(aptr0 + ko, a_d);
            async_ld16(aptr1 + ko, a_d + 1024);
            async_ld16(bptr0 + ko, b_d);
            async_ld16(bptr1 + ko, b_d + 1024);
        }
        __syncthreads();

        #pragma unroll
        for (int ks = 0; ks < 2; ++ks) {
            const unsigned short* cA = sA + ks * 4096;
            const unsigned short* cB = sB + ks * 4096;
            bf16x8 af[4], bfr[4];
            #pragma unroll
            for (int i = 0; i < 4; ++i)
                af[i] = *(const bf16x8*)&cA[(wm * 64 + i * 16 + l15) * 32 + quad * 8];
            #pragma unroll
            for (int j = 0; j < 4; ++j)
                bfr[j] = *(const bf16x8*)&cB[(wn * 64 + j * 16 + l15) * 32 + quad * 8];
            #pragma unroll
            for (int i = 0; i < 4; ++i)
                #pragma unroll
                for (int j = 0; j < 4; ++j)
                    acc[i][j] = __builtin_amdgcn_mfma_f32_16x16x32_bf16(af[i], bfr[j], acc[i][j], 0, 0, 0);
        }
    }

    #pragma unroll
    for (int i = 0; i < 4; ++i)
        #pragma unroll
        for (int r = 0; r < 4; ++r) {
            int m = m0 + wm * 64 + i * 16 + quad * 4 + r;   // row = quad*4+reg
            if (m < M) {
                #pragma unroll
                for (int j = 0; j < 4; ++j)
                    C[(size_t)m * 768 + n0 + wn * 64 + j * 16 + l15] = f2bf(acc[i][j][r]);
            }
        }
}

// ---- prep (role-partitioned): W transpose | matvec u=W@a | x conv + cur=0 ---
__global__ __launch_bounds__(256) void prep_kernel(
    const float* __restrict__ x, unsigned short* __restrict__ xb, int n8,
    const float* __restrict__ W1, const float* __restrict__ W2,
    unsigned short* __restrict__ Wt1, unsigned short* __restrict__ Wt2,
    const float* __restrict__ as1, const float* __restrict__ ad1,
    const float* __restrict__ as2, const float* __restrict__ ad2,
    float* __restrict__ us1, float* __restrict__ ud1,
    float* __restrict__ us2, float* __restrict__ ud2,
    int* __restrict__ cur, int N)
{
    int b = blockIdx.x, tid = threadIdx.x;
    if (b < 1152) {
        const float* W = (b >= 576) ? W2 : W1;
        unsigned short* Wt = (b >= 576) ? Wt2 : Wt1;
        int rem = (b >= 576) ? b - 576 : b;
        __shared__ float tile[32][33];
        int x0 = (rem % 24) * 32, y0 = (rem / 24) * 32;
        int tx = tid & 31, ty = tid >> 5;   // 32 x 8
        for (int r = ty; r < 32; r += 8)
            tile[r][tx] = W[(size_t)(y0 + r) * D_FEAT + x0 + tx];
        __syncthreads();
        for (int r = ty; r < 32; r += 8)
            Wt[(size_t)(x0 + r) * D_FEAT + y0 + tx] = f2bf(tile[tx][r]);
    } else if (b < 1344) {
        int lane = tid & 63;
        int k = (b - 1152) * 4 + (tid >> 6);
        const float* r1 = W1 + (size_t)k * D_FEAT + lane * 12;
        const float* r2 = W2 + (size_t)k * D_FEAT + lane * 12;
        float s1 = 0.f, d1 = 0.f, s2 = 0.f, d2 = 0.f;
        #pragma unroll
        for (int c = 0; c < 3; ++c) {
            float4 w1v = *(const float4*)(r1 + c * 4);
            float4 w2v = *(const float4*)(r2 + c * 4);
            int off = lane * 12 + c * 4;
            float4 a1 = *(const float4*)(as1 + off);
            float4 b1v = *(const float4*)(ad1 + off);
            float4 a2 = *(const float4*)(as2 + off);
            float4 b2v = *(const float4*)(ad2 + off);
            s1 += w1v.x * a1.x + w1v.y * a1.y + w1v.z * a1.z + w1v.w * a1.w;
            d1 += w1v.x * b1v.x + w1v.y * b1v.y + w1v.z * b1v.z + w1v.w * b1v.w;
            s2 += w2v.x * a2.x + w2v.y * a2.y + w2v.z * a2.z + w2v.w * a2.w;
            d2 += w2v.x * b2v.x + w2v.y * b2v.y + w2v.z * b2v.z + w2v.w * b2v.w;
        }
        #pragma unroll
        for (int m = 32; m >= 1; m >>= 1) {
            s1 += __shfl_xor(s1, m, 64); d1 += __shfl_xor(d1, m, 64);
            s2 += __shfl_xor(s2, m, 64); d2 += __shfl_xor(d2, m, 64);
        }
        if (lane == 0) { us1[k] = s1; ud1[k] = d1; us2[k] = s2; ud2[k] = d2; }
    } else {
        int li = (b - 1344) * 256 + tid;
        if (li < n8) {
            float4 v0 = ((const float4*)x)[li * 2];
            float4 v1 = ((const float4*)x)[li * 2 + 1];
            ushort4 o0, o1;
            o0.x = f2bf(v0.x); o0.y = f2bf(v0.y); o0.z = f2bf(v0.z); o0.w = f2bf(v0.w);
            o1.x = f2bf(v1.x); o1.y = f2bf(v1.y); o1.z = f2bf(v1.z); o1.w = f2bf(v1.w);
            ((ushort4*)xb)[li * 2] = o0;
            ((ushort4*)xb)[li * 2 + 1] = o1;
        }
        if (li < N) cur[li] = 0;
    }
}

// ---- mega1: GEMM-1 | CSR fill | layer-1 dots (role-partitioned) -------------
__global__ __launch_bounds__(256) void mega1_kernel(
    const unsigned short* __restrict__ A,    // xb [M,768] bf16
    const unsigned short* __restrict__ Bt,   // Wt1 [768,768] bf16
    unsigned short* __restrict__ C,          // h [M,768] bf16
    int M, int GB, int fB,
    const int* __restrict__ src, const int* __restrict__ dst, int E,
    int* __restrict__ cur, int* __restrict__ col,
    const float* __restrict__ us1, const float* __restrict__ ud1,
    float* __restrict__ es1, float* __restrict__ ed1)
{
    int b = blockIdx.x, tid = threadIdx.x;
    if (b < GB) {
        __shared__ __align__(16) unsigned short sA[2 * 128 * 32];   // 16 KB
        __shared__ __align__(16) unsigned short sB[2 * 128 * 32];   // 16 KB
        gemm_tile(A, Bt, C, M, (b / 6) * 128, (b % 6) * 128, sA, sB);
    } else if (b < GB + fB) {
        int i = (b - GB) * 256 + tid;
        if (i < E + M) {
            int s, d;
            if (i < E) { s = src[i]; d = dst[i]; } else { s = i - E; d = s; }
            int pos = atomicAdd(&cur[d], 1);
            if (pos < SLOT) col[d * SLOT + pos] = s;
        }
    } else {
        int lane = tid & 63;
        int n = (b - GB - fB) * 4 + (tid >> 6);
        if (n >= M) return;
        const unsigned short* xr = A + (size_t)n * D_FEAT + lane * 12;
        float s = 0.f, d = 0.f;
        #pragma unroll
        for (int c = 0; c < 3; ++c) {
            ushort4 v = *(const ushort4*)(xr + c * 4);
            int off = lane * 12 + c * 4;
            float4 u = *(const float4*)(us1 + off);
            float4 w = *(const float4*)(ud1 + off);
            float f0 = bf2f(v.x), f1 = bf2f(v.y), f2v = bf2f(v.z), f3 = bf2f(v.w);
            s += f0 * u.x + f1 * u.y + f2v * u.z + f3 * u.w;
            d += f0 * w.x + f1 * w.y + f2v * w.z + f3 * w.w;
        }
        #pragma unroll
        for (int m = 32; m >= 1; m >>= 1) {
            s += __shfl_xor(s, m, 64); d += __shfl_xor(d, m, 64);
        }
        if (lane == 0) { es1[n] = s; ed1[n] = d; }
    }
}

// ---- pure GEMM (layer 2) ----------------------------------------------------
__global__ __launch_bounds__(256) void gemm_kernel(
    const unsigned short* __restrict__ A, const unsigned short* __restrict__ Bt,
    unsigned short* __restrict__ C, int M)
{
    __shared__ __align__(16) unsigned short sA[2 * 128 * 32];
    __shared__ __align__(16) unsigned short sB[2 * 128 * 32];
    gemm_tile(A, Bt, C, M, blockIdx.x * 128, blockIdx.y * 128, sA, sB);
}

// ---- wave-per-node segment softmax + weighted aggregation (h bf16) ----------
__global__ __launch_bounds__(256) void agg_kernel(
    const unsigned short* __restrict__ h, const float* __restrict__ es,
    const float* __restrict__ ed, const int* __restrict__ cnt,
    const int* __restrict__ col, const float* __restrict__ bias,
    unsigned short* __restrict__ out_bf, float* __restrict__ out_f,
    const float* __restrict__ us2, const float* __restrict__ ud2,
    float* __restrict__ es2, float* __restrict__ ed2, int N)
{
    int wid = threadIdx.x >> 6, lane = threadIdx.x & 63;
    int n = blockIdx.x * 4 + wid;
    if (n >= N) return;
    int deg = cnt[n]; if (deg > SLOT) deg = SLOT;
    int beg = n * SLOT;
    float edn = ed[n];

    float a[12];
    #pragma unroll
    for (int k = 0; k < 12; ++k) a[k] = 0.f;
    const unsigned short* hb = h + lane * 12;

    if (deg <= 64) {
        int s = 0; float v = -3.4e38f;
        if (lane < deg) {
            s = col[beg + lane];
            v = es[s] + edn;
            v = v > 0.f ? v : 0.2f * v;
        }
        float lm = v;
        #pragma unroll
        for (int m = 32; m >= 1; m >>= 1) lm = fmaxf(lm, __shfl_xor(lm, m, 64));
        float w = (lane < deg) ? __expf(v - lm) : 0.f;
        float ls = w;
        #pragma unroll
        for (int m = 32; m >= 1; m >>= 1) ls += __shfl_xor(ls, m, 64);
        w *= (1.f / ls);

        int i = 0;
        for (; i + 4 <= deg; i += 4) {
            #pragma unroll
            for (int u = 0; u < 4; ++u) {
                int   su = __shfl(s, i + u, 64);
                float wu = __shfl(w, i + u, 64);
                const unsigned short* hr = hb + (size_t)su * 768;
                ushort4 p0 = *(const ushort4*)(hr);
                ushort4 p1 = *(const ushort4*)(hr + 4);
                ushort4 p2 = *(const ushort4*)(hr + 8);
                a[0]  += wu * bf2f(p0.x); a[1]  += wu * bf2f(p0.y);
                a[2]  += wu * bf2f(p0.z); a[3]  += wu * bf2f(p0.w);
                a[4]  += wu * bf2f(p1.x); a[5]  += wu * bf2f(p1.y);
                a[6]  += wu * bf2f(p1.z); a[7]  += wu * bf2f(p1.w);
                a[8]  += wu * bf2f(p2.x); a[9]  += wu * bf2f(p2.y);
                a[10] += wu * bf2f(p2.z); a[11] += wu * bf2f(p2.w);
            }
        }
        for (; i < deg; ++i) {
            int   s0 = __shfl(s, i, 64);
            float w0 = __shfl(w, i, 64);
            const unsigned short* h0 = hb + (size_t)s0 * 768;
            ushort4 p0 = *(const ushort4*)(h0);
            ushort4 p1 = *(const ushort4*)(h0 + 4);
            ushort4 p2 = *(const ushort4*)(h0 + 8);
            a[0]  += w0 * bf2f(p0.x); a[1]  += w0 * bf2f(p0.y);
            a[2]  += w0 * bf2f(p0.z); a[3]  += w0 * bf2f(p0.w);
            a[4]  += w0 * bf2f(p1.x); a[5]  += w0 * bf2f(p1.y);
            a[6]  += w0 * bf2f(p1.z); a[7]  += w0 * bf2f(p1.w);
            a[8]  += w0 * bf2f(p2.x); a[9]  += w0 * bf2f(p2.y);
            a[10] += w0 * bf2f(p2.z); a[11] += w0 * bf2f(p2.w);
        }
    } else {
        float lm = -3.4e38f;
        for (int i = lane; i < deg; i += 64) {
            float v = es[col[beg + i]] + edn;
            v = v > 0.f ? v : 0.2f * v;
            lm = fmaxf(lm, v);
        }
        #pragma unroll
        for (int m = 32; m >= 1; m >>= 1) lm = fmaxf(lm, __shfl_xor(lm, m, 64));
        float ls = 0.f;
        for (int i = lane; i < deg; i += 64) {
            float v = es[col[beg + i]] + edn;
            v = v > 0.f ? v : 0.2f * v;
            ls += __expf(v - lm);
        }
        #pragma unroll
        for (int m = 32; m >= 1; m >>= 1) ls += __shfl_xor(ls, m, 64);
        float rz = 1.f / ls;
        for (int i = 0; i < deg; ++i) {
            int sidx = col[beg + i];
            float u = es[sidx] + edn;
            u = u > 0.f ? u : 0.2f * u;
            float w = __expf(u - lm) * rz;
            const unsigned short* hr = hb + (size_t)sidx * 768;
            ushort4 v0 = *(const ushort4*)(hr);
            ushort4 v1 = *(const ushort4*)(hr + 4);
            ushort4 v2 = *(const ushort4*)(hr + 8);
            a[0]  += w * bf2f(v0.x); a[1]  += w * bf2f(v0.y);
            a[2]  += w * bf2f(v0.z); a[3]  += w * bf2f(v0.w);
            a[4]  += w * bf2f(v1.x); a[5]  += w * bf2f(v1.y);
            a[6]  += w * bf2f(v1.z); a[7]  += w * bf2f(v1.w);
            a[8]  += w * bf2f(v2.x); a[9]  += w * bf2f(v2.y);
            a[10] += w * bf2f(v2.z); a[11] += w * bf2f(v2.w);
        }
    }

    float4 bv0 = *(const float4*)&bias[lane * 12];
    float4 bv1 = *(const float4*)&bias[lane * 12 + 4];
    float4 bv2 = *(const float4*)&bias[lane * 12 + 8];
    float o[12];
    o[0] = a[0] + bv0.x; o[1] = a[1] + bv0.y; o[2] = a[2] + bv0.z; o[3] = a[3] + bv0.w;
    o[4] = a[4] + bv1.x; o[5] = a[5] + bv1.y; o[6] = a[6] + bv1.z; o[7] = a[7] + bv1.w;
    o[8] = a[8] + bv2.x; o[9] = a[9] + bv2.y; o[10] = a[10] + bv2.z; o[11] = a[11] + bv2.w;
    size_t base = (size_t)n * 768 + lane * 12;
    if (out_bf) {   // layer 1: relu + bf16; fused es2/ed2 dots
        #pragma unroll
        for (int k = 0; k < 12; ++k) o[k] = fmaxf(o[k], 0.f);
        float ps = 0.f, pd = 0.f;
        #pragma unroll
        for (int c = 0; c < 3; ++c) {
            int off = lane * 12 + c * 4;
            float4 u = *(const float4*)(us2 + off);
            float4 w = *(const float4*)(ud2 + off);
            ps += o[c*4] * u.x + o[c*4+1] * u.y + o[c*4+2] * u.z + o[c*4+3] * u.w;
            pd += o[c*4] * w.x + o[c*4+1] * w.y + o[c*4+2] * w.z + o[c*4+3] * w.w;
        }
        #pragma unroll
        for (int m = 32; m >= 1; m >>= 1) {
            ps += __shfl_xor(ps, m, 64); pd += __shfl_xor(pd, m, 64);
        }
        if (lane == 0) { es2[n] = ps; ed2[n] = pd; }
        ushort4 w0, w1, w2;
        w0.x = f2bf(o[0]); w0.y = f2bf(o[1]); w0.z = f2bf(o[2]); w0.w = f2bf(o[3]);
        w1.x = f2bf(o[4]); w1.y = f2bf(o[5]); w1.z = f2bf(o[6]); w1.w = f2bf(o[7]);
        w2.x = f2bf(o[8]); w2.y = f2bf(o[9]); w2.z = f2bf(o[10]); w2.w = f2bf(o[11]);
        *(ushort4*)&out_bf[base] = w0;
        *(ushort4*)&out_bf[base + 4] = w1;
        *(ushort4*)&out_bf[base + 8] = w2;
    } else {        // layer 2: f32 final output
        float4 f0 = {o[0], o[1], o[2], o[3]};
        float4 f1 = {o[4], o[5], o[6], o[7]};
        float4 f2 = {o[8], o[9], o[10], o[11]};
        *(float4*)&out_f[base] = f0;
        *(float4*)&out_f[base + 4] = f1;
        *(float4*)&out_f[base + 8] = f2;
    }
}

// -----------------------------------------------------------------------------
extern "C" void kernel_launch(void* const* d_in, const int* in_sizes, int n_in,
                              void* d_out, int out_size, void* d_ws, size_t ws_size,
                              hipStream_t stream)
{
    const float* x   = (const float*)d_in[0];
    const int*   ei  = (const int*)d_in[1];
    const float* W1  = (const float*)d_in[2];
    const float* as1 = (const float*)d_in[3];
    const float* ad1 = (const float*)d_in[4];
    const float* b1  = (const float*)d_in[5];
    const float* W2  = (const float*)d_in[6];
    const float* as2 = (const float*)d_in[7];
    const float* ad2 = (const float*)d_in[8];
    const float* b2  = (const float*)d_in[9];

    const int N = in_sizes[0] / D_FEAT;
    const int E = in_sizes[1] / 2;
    const int* src = ei;
    const int* dst = ei + E;

    char* ws = (char*)d_ws;
    size_t off = 0;
    auto alloc = [&](size_t bytes) -> void* {
        void* p = ws + off;
        off += (bytes + 255) & ~(size_t)255;
        return p;
    };
    unsigned short* Wt1  = (unsigned short*)alloc((size_t)768 * 768 * 2);
    unsigned short* Wt2  = (unsigned short*)alloc((size_t)768 * 768 * 2);
    unsigned short* xb   = (unsigned short*)alloc((size_t)N * 768 * 2);
    unsigned short* h    = (unsigned short*)alloc((size_t)N * 768 * 2);
    unsigned short* x2b  = (unsigned short*)alloc((size_t)N * 768 * 2);
    float*          us1  = (float*)alloc((size_t)768 * 4);
    float*          ud1  = (float*)alloc((size_t)768 * 4);
    float*          us2  = (float*)alloc((size_t)768 * 4);
    float*          ud2  = (float*)alloc((size_t)768 * 4);
    float*          es1  = (float*)alloc((size_t)N * 4);
    float*          ed1  = (float*)alloc((size_t)N * 4);
    float*          es2  = (float*)alloc((size_t)N * 4);
    float*          ed2  = (float*)alloc((size_t)N * 4);
    int*            cur  = (int*)alloc((size_t)N * 4);
    int*            col  = (int*)alloc((size_t)N * SLOT * 4);

    // dispatch 1: prep (transpose + matvec + conv + cur=0)
    int n8 = N * 768 / 8;
    prep_kernel<<<1344 + (n8 + 255) / 256, 256, 0, stream>>>(
        x, xb, n8, W1, W2, Wt1, Wt2, as1, ad1, as2, ad2,
        us1, ud1, us2, ud2, cur, N);

    // dispatch 2: mega1 = GEMM-1 + CSR fill + layer-1 dots
    int mB = (N + 127) / 128;            // 79
    int GB = mB * 6;                     // gemm blocks
    int fB = (E + N + 255) / 256;        // fill blocks
    int dB = (N + 3) / 4;                // dots blocks
    mega1_kernel<<<GB + fB + dB, 256, 0, stream>>>(
        xb, Wt1, h, N, GB, fB, src, dst, E, cur, col, us1, ud1, es1, ed1);

    // dispatch 3: agg layer 1 (+ fused es2/ed2)
    agg_kernel<<<dB, 256, 0, stream>>>(h, es1, ed1, cur, col, b1,
                                       x2b, nullptr, us2, ud2, es2, ed2, N);
    // dispatch 4: GEMM-2
    dim3 ggrid(mB, 6);
    gemm_kernel<<<ggrid, 256, 0, stream>>>(x2b, Wt2, h, N);
    // dispatch 5: agg layer 2 -> f32 out
    agg_kernel<<<dB, 256, 0, stream>>>(h, es2, ed2, cur, col, b2,
                                       nullptr, (float*)d_out,
                                       nullptr, nullptr, nullptr, nullptr, N);
}